// Round 6
// baseline (819.621 us; speedup 1.0000x reference)
//
#include <hip/hip_runtime.h>

typedef _Float16 f16x8  __attribute__((ext_vector_type(8)));
typedef _Float16 f16x4  __attribute__((ext_vector_type(4)));
typedef float    f32x4  __attribute__((ext_vector_type(4)));
typedef float    f32x16 __attribute__((ext_vector_type(16)));

// ---------------------------------------------------------------- helpers

__device__ __forceinline__ void async16(void* lds, const void* g) {
    __builtin_amdgcn_global_load_lds(
        (const __attribute__((address_space(1))) unsigned int*)g,
        (__attribute__((address_space(3))) unsigned int*)lds, 16, 0, 0);
}

#define MEMF() asm volatile("" ::: "memory")
__device__ __forceinline__ void BAR() { MEMF(); __builtin_amdgcn_s_barrier(); MEMF(); }
#define VMWAIT(N) asm volatile("s_waitcnt vmcnt(" #N ")" ::: "memory")

// ------------------------------------------------- balanced 4-phase 256x256 GEMM
// A [M][K] fp16, BT [N][K] fp16, C = (A*BT^T)*alpha+beta  [M][N] fp32
// 8 waves (2Mx4N), BK=64, dbuf-2 LDS (128KiB), MFMA 32x32x16.
// Per K-tile: 4 phases with BALANCED reads (8,4,8,4)/wave and 8 MFMA each
// (quadrant = mi-pair x ks-pair), 5 barriers, stage-all at ph1, vmcnt(0) at
// ph4 (waits ~3-phase-old loads => ~free).
//
// Ledger: tile T in buf P=T&1. ph1 stages tile T+1 into P^1. WAR: tile T-1
// (buf P^1) frags last read at its ph4; those reads lgkm-drain before its ph4
// MFMA, which precedes its final barrier; our stage issues after => safe.
// RAW: VMWAIT(0)+BAR at T's end => T+1 fully in LDS before any T+1 read.
// LDS rows = 128B (8 slots of 16B); swizzle slot ^= (row&7) == per-lane XOR
// (lane&7)<<4 on reads; staging pre-applies the same involution to the global
// source column, LDS dest stays linear (gload_lds requirement).

__global__ __launch_bounds__(512, 2) void gemm_f16_bn_8p(
        const _Float16* __restrict__ A, const _Float16* __restrict__ BT,
        float* __restrict__ C,
        const float* __restrict__ bias, const float* __restrict__ mean,
        const float* __restrict__ var,  const float* __restrict__ bnw,
        const float* __restrict__ bnb,  const float* __restrict__ scalep,
        int M, int N, int K) {
    __shared__ __align__(16) _Float16 ldsA[2][16384];   // 2 x 256x64 fp16 = 64KB
    __shared__ __align__(16) _Float16 ldsB[2][16384];   // 64KB

    const char* const ldsAc = (const char*)&ldsA[0][0];
    const char* const ldsBc = (const char*)&ldsB[0][0];

    // bijective XCD swizzle (grid = 1024, divisible by 8)
    const int nwg = gridDim.x;
    const int cpx = nwg >> 3;
    int bid = blockIdx.x;
    int swzb = ((nwg & 7) == 0) ? (bid & 7) * cpx + (bid >> 3) : bid;
    const int ntn = N >> 8;
    const int m0 = (swzb / ntn) << 8, n0 = (swzb % ntn) << 8;

    const int t = threadIdx.x;
    const int lane = t & 63, wid = t >> 6;
    const int wr = wid >> 2, wc = wid & 3;          // 2M x 4N waves
    const int l31 = lane & 31, lh = lane >> 5;
    const int swz = (lane & 7) << 4;

    const int aoff = (wr * 128 + l31) * 128;        // per-lane A row byte base
    const int boff = (wc * 64 + l31) * 128;         // per-lane B row byte base
    int cs[4];
#pragma unroll
    for (int s = 0; s < 4; s++) cs[s] = ((2 * s + lh) << 4) ^ swz;

#define FA(P, MI, S) (*(const f16x8*)(ldsAc + (P) * 32768 + aoff + (MI) * 4096 + cs[S]))
#define FB(P, NI, S) (*(const f16x8*)(ldsBc + (P) * 32768 + boff + (NI) * 4096 + cs[S]))

    // staging: chunk c (of 2048 per operand tile) -> LDS byte c*16 (linear);
    // row = c>>3 within 64-row quarter, slot = c&7; source column pre-XORed.
    const int srcc = ((t & 7) ^ ((t >> 3) & 7)) << 3;
    const _Float16* const baseA = A  + (size_t)(m0 + (t >> 3)) * K + srcc;
    const _Float16* const baseB = BT + (size_t)(n0 + (t >> 3)) * K + srcc;
    char* const adst = (char*)&ldsA[0][0] + (size_t)t * 16;
    char* const bdst = (char*)&ldsB[0][0] + (size_t)t * 16;

#define STAGE(P, T_)                                                      \
  do {                                                                    \
    const _Float16* sA_ = baseA + (size_t)(T_) * 64;                      \
    const _Float16* sB_ = baseB + (size_t)(T_) * 64;                      \
    char* aX_ = adst + (P) * 32768;                                       \
    char* bX_ = bdst + (P) * 32768;                                       \
    async16(aX_,         sA_);                                            \
    async16(aX_ + 8192,  sA_ + (size_t)64  * K);                          \
    async16(aX_ + 16384, sA_ + (size_t)128 * K);                          \
    async16(aX_ + 24576, sA_ + (size_t)192 * K);                          \
    async16(bX_,         sB_);                                            \
    async16(bX_ + 8192,  sB_ + (size_t)64  * K);                          \
    async16(bX_ + 16384, sB_ + (size_t)128 * K);                          \
    async16(bX_ + 24576, sB_ + (size_t)192 * K);                          \
  } while (0)

    f16x8 af0[2], af1[2], ag0[2], ag1[2], bf0[2], bf1[2];
    f32x16 acc[4][2] = {};

    const int NT = K >> 6;   // host gate: even, >= 2

#define MFMA8(A0, A1, R0, R1)                                             \
  do {                                                                    \
    __builtin_amdgcn_s_setprio(1);                                        \
    _Pragma("unroll")                                                     \
    for (int s = 0; s < 2; s++) {                                         \
      acc[R0][0] = __builtin_amdgcn_mfma_f32_32x32x16_f16(A0[s], bf0[s], acc[R0][0], 0, 0, 0); \
      acc[R0][1] = __builtin_amdgcn_mfma_f32_32x32x16_f16(A0[s], bf1[s], acc[R0][1], 0, 0, 0); \
      acc[R1][0] = __builtin_amdgcn_mfma_f32_32x32x16_f16(A1[s], bf0[s], acc[R1][0], 0, 0, 0); \
      acc[R1][1] = __builtin_amdgcn_mfma_f32_32x32x16_f16(A1[s], bf1[s], acc[R1][1], 0, 0, 0); \
    }                                                                     \
    __builtin_amdgcn_s_setprio(0);                                        \
  } while (0)

#define TILE(P, T_)                                                       \
  do {                                                                    \
    _Pragma("unroll")                                                     \
    for (int s = 0; s < 2; s++) {                                         \
      af0[s] = FA(P, 0, s); af1[s] = FA(P, 1, s);                         \
      bf0[s] = FB(P, 0, s); bf1[s] = FB(P, 1, s);                         \
    }                                                                     \
    if ((T_) + 1 < NT) STAGE((P) ^ 1, (T_) + 1);                          \
    BAR();                                                                \
    MFMA8(af0, af1, 0, 1);                                                \
    _Pragma("unroll")                                                     \
    for (int s = 0; s < 2; s++) { ag0[s] = FA(P, 2, s); ag1[s] = FA(P, 3, s); } \
    BAR();                                                                \
    MFMA8(ag0, ag1, 2, 3);                                                \
    _Pragma("unroll")                                                     \
    for (int s = 0; s < 2; s++) {                                         \
      af0[s] = FA(P, 0, s + 2); af1[s] = FA(P, 1, s + 2);                 \
      bf0[s] = FB(P, 0, s + 2); bf1[s] = FB(P, 1, s + 2);                 \
    }                                                                     \
    BAR();                                                                \
    MFMA8(af0, af1, 0, 1);                                                \
    _Pragma("unroll")                                                     \
    for (int s = 0; s < 2; s++) { ag0[s] = FA(P, 2, s + 2); ag1[s] = FA(P, 3, s + 2); } \
    BAR();                                                                \
    MFMA8(ag0, ag1, 2, 3);                                                \
    VMWAIT(0);                                                            \
    BAR();                                                                \
  } while (0)

    // prologue: stage tile 0 into buf 0
    STAGE(0, 0);
    VMWAIT(0);
    BAR();

    for (int ti = 0; ti < NT; ti += 2) {
        TILE(0, ti);
        TILE(1, ti + 1);
    }
#undef TILE
#undef MFMA8
#undef STAGE
#undef FA
#undef FB

    // fused BN-affine epilogue, nontemporal fp32 stores
    // C/D layout 32x32: col = lane&31, row = (r&3) + 8*(r>>2) + 4*(lane>>5)
    const float sc = scalep[0];
#pragma unroll
    for (int ni = 0; ni < 2; ni++) {
        const int col = n0 + wc * 64 + ni * 32 + l31;
        const float rv    = rsqrtf(var[col] + 1e-5f);
        const float alpha = rv * bnw[col] * sc;
        const float beta  = (bias[col] - mean[col]) * alpha + bnb[col] * sc;
#pragma unroll
        for (int mi = 0; mi < 4; mi++) {
            const int rowb = m0 + wr * 128 + mi * 32 + 4 * lh;
#pragma unroll
            for (int r = 0; r < 16; r++) {
                const int row = rowb + (r & 3) + 8 * (r >> 2);
                __builtin_nontemporal_store(acc[mi][ni][r] * alpha + beta,
                    &C[(size_t)row * N + col]);
            }
        }
    }
}

// ---------------------------------------------------------------- converts

__global__ __launch_bounds__(256) void cvt_x_kernel(const float4* __restrict__ in,
                                                    f16x4* __restrict__ outp, long n4) {
    long i = (long)blockIdx.x * blockDim.x + threadIdx.x;
    const long stride = (long)gridDim.x * blockDim.x;
    for (; i < n4; i += stride) {
        float4 v = in[i];
        f16x4 h = { (_Float16)v.x, (_Float16)v.y, (_Float16)v.z, (_Float16)v.w };
        outp[i] = h;
    }
}

// w [K][N] fp32 -> wt [N][K] fp16
__global__ __launch_bounds__(256) void transpose_w_kernel(const float* __restrict__ w,
                                                          _Float16* __restrict__ wt,
                                                          int K, int N) {
    __shared__ _Float16 tile[32][33];
    const int n0 = blockIdx.x * 32;
    const int k0 = blockIdx.y * 32;
    for (int i = threadIdx.y; i < 32; i += 8)
        tile[i][threadIdx.x] = (_Float16)w[(size_t)(k0 + i) * N + n0 + threadIdx.x];
    __syncthreads();
    for (int i = threadIdx.y; i < 32; i += 8)
        wt[(size_t)(n0 + i) * K + k0 + threadIdx.x] = tile[threadIdx.x][i];
}

// ------------------------------------------------- fallback GEMM (no ws)

__device__ __forceinline__ void mfma_step_128(const _Float16* As, const _Float16* Bs,
                                              f32x4 (&acc)[4][4], int lane, int wr, int wc) {
    const int kk = (lane >> 4) * 8;
    const int rr = lane & 15;
    f16x8 af[4], bf[4];
#pragma unroll
    for (int mi = 0; mi < 4; mi++)
        af[mi] = *(const f16x8*)(As + (size_t)(wr * 64 + mi * 16 + rr) * 32 + kk);
#pragma unroll
    for (int ni = 0; ni < 4; ni++)
        bf[ni] = *(const f16x8*)(Bs + (size_t)(wc * 64 + ni * 16 + rr) * 32 + kk);
#pragma unroll
    for (int mi = 0; mi < 4; mi++)
#pragma unroll
        for (int ni = 0; ni < 4; ni++)
            acc[mi][ni] = __builtin_amdgcn_mfma_f32_16x16x32_f16(af[mi], bf[ni], acc[mi][ni], 0, 0, 0);
}

__global__ __launch_bounds__(256) void gemm_f32src_bn(const float* __restrict__ X,
                                                      const float* __restrict__ W,
                                                      float* __restrict__ C,
                                                      const float* __restrict__ bias,
                                                      const float* __restrict__ mean,
                                                      const float* __restrict__ var,
                                                      const float* __restrict__ bnw,
                                                      const float* __restrict__ bnb,
                                                      const float* __restrict__ scalep,
                                                      int M, int N, int K) {
    __shared__ _Float16 As[128 * 32];
    __shared__ _Float16 Bs[128 * 32];

    const int nwg = gridDim.x;
    const int cpx = nwg >> 3;
    int bid = blockIdx.x;
    int swz = ((nwg & 7) == 0) ? (bid & 7) * cpx + (bid >> 3) : bid;
    const int ntn = N / 128;
    const int m0 = (swz / ntn) * 128, n0 = (swz % ntn) * 128;

    const int t = threadIdx.x;
    const int lane = t & 63, w = t >> 6;
    const int wr = w >> 1, wc = w & 1;

    f32x4 acc[4][4] = {};

    for (int k0 = 0; k0 < K; k0 += 32) {
        __syncthreads();
#pragma unroll
        for (int p = 0; p < 4; p++) {
            const int r = p * 32 + (t >> 3);
            const int c = (t & 7) * 4;
            float4 v = *(const float4*)&X[(size_t)(m0 + r) * K + k0 + c];
            f16x4 h = { (_Float16)v.x, (_Float16)v.y, (_Float16)v.z, (_Float16)v.w };
            *(f16x4*)&As[(size_t)r * 32 + c] = h;
        }
#pragma unroll
        for (int p = 0; p < 4; p++) {
            const int kk = p * 8 + (t >> 5);
            const int nn = (t & 31) * 4;
            float4 v = *(const float4*)&W[(size_t)(k0 + kk) * N + n0 + nn];
            Bs[(size_t)(nn + 0) * 32 + kk] = (_Float16)v.x;
            Bs[(size_t)(nn + 1) * 32 + kk] = (_Float16)v.y;
            Bs[(size_t)(nn + 2) * 32 + kk] = (_Float16)v.z;
            Bs[(size_t)(nn + 3) * 32 + kk] = (_Float16)v.w;
        }
        __syncthreads();
        mfma_step_128(As, Bs, acc, lane, wr, wc);
    }

    const float s = scalep[0];
    const int colbase = n0 + wc * 64 + (lane & 15);
    const int rowbase = m0 + wr * 64 + ((lane >> 4) << 2);
#pragma unroll
    for (int ni = 0; ni < 4; ni++) {
        const int col = colbase + ni * 16;
        const float r     = rsqrtf(var[col] + 1e-5f);
        const float alpha = r * bnw[col] * s;
        const float beta  = (bias[col] - mean[col]) * alpha + bnb[col] * s;
#pragma unroll
        for (int mi = 0; mi < 4; mi++)
#pragma unroll
            for (int i = 0; i < 4; i++)
                C[(size_t)(rowbase + mi * 16 + i) * N + col] = acc[mi][ni][i] * alpha + beta;
    }
}

// ---------------------------------------------------------------- softmax

__global__ __launch_bounds__(256) void softmax_rows(float* __restrict__ out, int N) {
    __shared__ float red[8];
    float4* p = (float4*)(out + (size_t)blockIdx.x * N);
    const int t = threadIdx.x;
    const int lane = t & 63, wid = t >> 6;

    float4 v[4];
    float mx = -3.4e38f;
#pragma unroll
    for (int i = 0; i < 4; i++) {
        v[i] = p[t + 256 * i];
        mx = fmaxf(mx, fmaxf(fmaxf(v[i].x, v[i].y), fmaxf(v[i].z, v[i].w)));
    }
#pragma unroll
    for (int off = 32; off >= 1; off >>= 1) mx = fmaxf(mx, __shfl_xor(mx, off));
    if (lane == 0) red[wid] = mx;
    __syncthreads();
    mx = fmaxf(fmaxf(red[0], red[1]), fmaxf(red[2], red[3]));

    float sum = 0.f;
#pragma unroll
    for (int i = 0; i < 4; i++) {
        v[i].x = __expf(v[i].x - mx); v[i].y = __expf(v[i].y - mx);
        v[i].z = __expf(v[i].z - mx); v[i].w = __expf(v[i].w - mx);
        sum += v[i].x + v[i].y + v[i].z + v[i].w;
    }
#pragma unroll
    for (int off = 32; off >= 1; off >>= 1) sum += __shfl_xor(sum, off);
    if (lane == 0) red[4 + wid] = sum;
    __syncthreads();
    sum = red[4] + red[5] + red[6] + red[7];

    const float inv = 1.0f / sum;
#pragma unroll
    for (int i = 0; i < 4; i++) {
        v[i].x *= inv; v[i].y *= inv; v[i].z *= inv; v[i].w *= inv;
        p[t + 256 * i] = v[i];
    }
}

// ---------------------------------------------------------------- launch

extern "C" void kernel_launch(void* const* d_in, const int* in_sizes, int n_in,
                              void* d_out, int out_size, void* d_ws, size_t ws_size,
                              hipStream_t stream) {
    const float* x     = (const float*)d_in[0];
    const float* w     = (const float*)d_in[1];
    const float* bias  = (const float*)d_in[2];
    const float* mean  = (const float*)d_in[3];
    const float* var   = (const float*)d_in[4];
    const float* bnw   = (const float*)d_in[5];
    const float* bnb   = (const float*)d_in[6];
    const float* scale = (const float*)d_in[7];
    float* out = (float*)d_out;

    const int N = in_sizes[2];
    const int K = in_sizes[1] / N;
    const int M = in_sizes[0] / K;

    const size_t xh_bytes = (size_t)M * K * sizeof(_Float16);
    const size_t wh_bytes = (size_t)N * K * sizeof(_Float16);
    const int NT = K >> 6;

    if (ws_size >= xh_bytes + wh_bytes && (M & 255) == 0 && (N & 255) == 0 &&
        (K & 63) == 0 && NT >= 2 && (NT & 1) == 0) {
        _Float16* x16 = (_Float16*)d_ws;
        _Float16* wt16 = (_Float16*)((char*)d_ws + xh_bytes);
        cvt_x_kernel<<<2048, 256, 0, stream>>>((const float4*)x, (f16x4*)x16,
                                               (long)M * K / 4);
        transpose_w_kernel<<<dim3(N / 32, K / 32), dim3(32, 8), 0, stream>>>(w, wt16, K, N);
        const int nblocks = (M >> 8) * (N >> 8);
        gemm_f16_bn_8p<<<nblocks, 512, 0, stream>>>(x16, wt16, out, bias, mean, var,
                                                    bnw, bnb, scale, M, N, K);
    } else {
        const int nblocks = (M / 128) * (N / 128);
        gemm_f32src_bn<<<nblocks, 256, 0, stream>>>(x, w, out, bias, mean, var,
                                                    bnw, bnb, scale, M, N, K);
    }
    softmax_rows<<<M, 256, 0, stream>>>(out, N);
}